// Round 11
// baseline (793.246 us; speedup 1.0000x reference)
//
#include <hip/hip_runtime.h>
#include <hip/hip_bf16.h>
#include <stdint.h>

#define M_TOK 4096
#define DDIM  2048
#define HDIM  2816
#define NEXP  8
#define PMAX  10240     // 40 * 256 >= 8192 + 8*255
#define MAXTILES 40
#define NB1   22        // HDIM / 128 (gemm1 col blocks: 128 gate + 128 up)
#define NB2   8         // DDIM / 256 (gemm2 col blocks)
#define NKT1  32        // DDIM / 64
#define NKT2  44        // HDIM / 64

typedef __attribute__((ext_vector_type(8))) short short8;
typedef __attribute__((ext_vector_type(4))) float f32x4;

#define GLD16(g, l) __builtin_amdgcn_global_load_lds(                              \
    (const __attribute__((address_space(1))) unsigned int*)(g),                    \
    (__attribute__((address_space(3))) unsigned int*)(l), 16, 0, 0)

#define VMCNT(n) asm volatile("s_waitcnt vmcnt(" #n ")" ::: "memory")

__device__ __forceinline__ unsigned short f2bf(float f) {
  unsigned int u = __float_as_uint(f);
  u += 0x7fffu + ((u >> 16) & 1u);
  return (unsigned short)(u >> 16);
}
__device__ __forceinline__ float bf2f(unsigned short u) {
  return __uint_as_float(((unsigned)u) << 16);
}

// ---------------- fp32 -> bf16 bulk convert (w1+w2) + init fused ----------------
__global__ void cvt2_bf16_k(const float4* __restrict__ in1, ushort4* __restrict__ out1, int n1,
                            const float4* __restrict__ in2, ushort4* __restrict__ out2, int n2,
                            int* __restrict__ tok, int* __restrict__ counts,
                            int* __restrict__ cursors) {
  int gid = blockIdx.x * blockDim.x + threadIdx.x;
  if (gid < PMAX) tok[gid] = -1;
  if (gid < NEXP) { counts[gid] = 0; cursors[gid] = 0; }
  const int stride = gridDim.x * blockDim.x;
  const int total = n1 + n2;
  int i = gid;
  for (; i + stride < total; i += 2 * stride) {
    int ia = i, ib = i + stride;
    float4 va = (ia < n1) ? in1[ia] : in2[ia - n1];
    float4 vb = (ib < n1) ? in1[ib] : in2[ib - n1];
    ushort4 oa, ob;
    oa.x = f2bf(va.x); oa.y = f2bf(va.y); oa.z = f2bf(va.z); oa.w = f2bf(va.w);
    ob.x = f2bf(vb.x); ob.y = f2bf(vb.y); ob.z = f2bf(vb.z); ob.w = f2bf(vb.w);
    if (ia < n1) out1[ia] = oa; else out2[ia - n1] = oa;
    if (ib < n1) out1[ib] = ob; else out2[ib - n1] = ob;
  }
  if (i < total) {
    float4 v = (i < n1) ? in1[i] : in2[i - n1];
    ushort4 o;
    o.x = f2bf(v.x); o.y = f2bf(v.y); o.z = f2bf(v.z); o.w = f2bf(v.w);
    if (i < n1) out1[i] = o; else out2[i - n1] = o;
  }
}

// ---------------- router (fused x->bf16 conversion) ----------------
__global__ __launch_bounds__(256) void router_k(const float4* __restrict__ x4,
                                                const float4* __restrict__ rw4,
                                                ushort4* __restrict__ xb4,
                                                float* __restrict__ wgt,
                                                int* __restrict__ eid,
                                                int* __restrict__ counts) {
  int lane = threadIdx.x & 63;
  int wv = threadIdx.x >> 6;
  int t = blockIdx.x * 4 + wv;
  int base = t * (DDIM / 4);
  float acc[NEXP];
#pragma unroll
  for (int e = 0; e < NEXP; ++e) acc[e] = 0.f;
#pragma unroll
  for (int j = 0; j < DDIM / 4 / 64; ++j) {
    float4 v = x4[base + j * 64 + lane];
    ushort4 o;
    o.x = f2bf(v.x); o.y = f2bf(v.y); o.z = f2bf(v.z); o.w = f2bf(v.w);
    xb4[base + j * 64 + lane] = o;
#pragma unroll
    for (int e = 0; e < NEXP; ++e) {
      float4 w = rw4[e * (DDIM / 4) + j * 64 + lane];
      acc[e] += v.x * w.x + v.y * w.y + v.z * w.z + v.w * w.w;
    }
  }
#pragma unroll
  for (int e = 0; e < NEXP; ++e) {
#pragma unroll
    for (int s = 32; s > 0; s >>= 1) acc[e] += __shfl_xor(acc[e], s, 64);
  }
  if (lane == 0) {
    float mx = acc[0];
#pragma unroll
    for (int e = 1; e < NEXP; ++e) mx = fmaxf(mx, acc[e]);
    float p[NEXP];
#pragma unroll
    for (int e = 0; e < NEXP; ++e) p[e] = expf(acc[e] - mx);
    int e0 = 0; float p0 = p[0];
#pragma unroll
    for (int e = 1; e < NEXP; ++e) if (p[e] > p0) { p0 = p[e]; e0 = e; }
    int e1 = -1; float p1 = -1.f;
#pragma unroll
    for (int e = 0; e < NEXP; ++e) if (e != e0 && p[e] > p1) { p1 = p[e]; e1 = e; }
    float s = p0 + p1;
    wgt[2 * t] = p0 / s; wgt[2 * t + 1] = p1 / s;
    eid[2 * t] = e0;     eid[2 * t + 1] = e1;
    atomicAdd(&counts[e0], 1);
    atomicAdd(&counts[e1], 1);
  }
}

// ---------------- offsets + tile map (256-row tiles, shared) ----------------
__global__ void offsets_k(const int* __restrict__ counts, int* __restrict__ offs,
                          int* __restrict__ tile2exp, int* __restrict__ tilerow,
                          int* __restrict__ ntiles) {
  if (threadIdx.x == 0 && blockIdx.x == 0) {
    int o = 0, nt = 0;
    for (int e = 0; e < NEXP; ++e) {
      offs[e] = o;
      int c = counts[e];
      int pt = (c + 255) >> 8;
      for (int i = 0; i < pt; ++i) { tile2exp[nt] = e; tilerow[nt] = o + i * 256; ++nt; }
      o += pt << 8;
    }
    offs[NEXP] = o;
    ntiles[0] = nt;
  }
}

// ---------------- scatter ----------------
__global__ void scatter_k(const int* __restrict__ eid, const int* __restrict__ offs,
                          int* __restrict__ cursors, int* __restrict__ tok,
                          int* __restrict__ slot) {
  int t = blockIdx.x * blockDim.x + threadIdx.x;
  if (t >= M_TOK) return;
#pragma unroll
  for (int k = 0; k < 2; ++k) {
    int e = eid[2 * t + k];
    int p = offs[e] + atomicAdd(&cursors[e], 1);
    tok[p] = t;
    slot[2 * t + k] = p;
  }
}

// ====== shared pipeline pieces: 512 thr, BM=256, BN=256(rows), BK=64 ======
// LDS: A dbuf0 | A dbuf1 | B dbuf0 | B dbuf1, each 32KB = [256 rows][64 bf16].
// Row = 128B = 8 granules of 16B; physical granule = logical ^ (row&7)
// (2-way bank aliasing on ds_read_b128 = free). k-step s=1 reads = offset^64.
// Per iter: stage kt+1 (8 gloads) -> vmcnt(8) -> barrier -> 24 ds_read +
// 64 MFMA -> barrier. Loads awaited one full iteration after issue.

#define STG8(KT, D)                                                                \
  { size_t kb_ = (size_t)(KT) * 128;                                               \
    char* Ad_ = ldsp + (D) * 32768 + tid * 16;                                     \
    char* Bd_ = ldsp + 65536 + (D) * 32768 + tid * 16;                             \
    _Pragma("unroll") for (int u_ = 0; u_ < 4; ++u_) {                             \
      GLD16(aSrc[u_] + kb_, Ad_ + u_ * 8192);                                      \
      GLD16(bSrc[u_] + kb_, Bd_ + u_ * 8192);                                      \
    } }

#define KBODY(AB, BB)                                                              \
  _Pragma("unroll") for (int s_ = 0; s_ < 2; ++s_) {                               \
    short8 a_[8], b_[4];                                                           \
    int sx_ = s_ << 6;                                                             \
    _Pragma("unroll") for (int i_ = 0; i_ < 8; ++i_)                               \
      a_[i_] = *(const short8*)((AB) + (aoff[i_] ^ sx_));                          \
    _Pragma("unroll") for (int i_ = 0; i_ < 4; ++i_)                               \
      b_[i_] = *(const short8*)((BB) + (boff[i_] ^ sx_));                          \
    __builtin_amdgcn_s_setprio(1);                                                 \
    _Pragma("unroll") for (int mi_ = 0; mi_ < 8; ++mi_)                            \
      _Pragma("unroll") for (int ni_ = 0; ni_ < 4; ++ni_)                          \
        acc[mi_][ni_] = __builtin_amdgcn_mfma_f32_16x16x32_bf16(a_[mi_], b_[ni_], acc[mi_][ni_], 0, 0, 0); \
    __builtin_amdgcn_s_setprio(0);                                                 \
  }

// =============== GEMM1: 256 slots x (128 gate + 128 up), K=2048 ===============
__global__ __launch_bounds__(512, 1) void gemm1_k(const unsigned short* __restrict__ xb,
                                                  const unsigned short* __restrict__ w1b,
                                                  const int* __restrict__ tok,
                                                  const int* __restrict__ tile2exp,
                                                  const int* __restrict__ tilerow,
                                                  const int* __restrict__ ntiles,
                                                  unsigned short* __restrict__ h) {
  __shared__ char ldsp[131072];
  int mt = blockIdx.x;
  if (mt >= ntiles[0]) return;
  int e = tile2exp[mt], r0 = tilerow[mt];
  int n0 = blockIdx.y * 128;
  int tid = threadIdx.x, lane = tid & 63;
  int wv = tid >> 6, wm = wv >> 2, wn = wv & 3;
  int l15 = lane & 15, lq = lane >> 4;

  // staging sources: 4 slots per thread per matrix (rows srow + u*64)
  int srow = tid >> 3, sq = tid & 7;
  const char* aSrc[4]; const char* bSrc[4];
#pragma unroll
  for (int u = 0; u < 4; ++u) {
    int r = srow + u * 64;
    int t = tok[r0 + r]; if (t < 0) t = 0;
    aSrc[u] = (const char*)xb + (size_t)t * (DDIM * 2) + ((sq ^ (r & 7)) << 4);
    int w1row = e * (2 * HDIM) + (r < 128 ? n0 + r : HDIM + n0 + (r - 128));
    bSrc[u] = (const char*)w1b + (size_t)w1row * (DDIM * 2) + ((sq ^ (r & 7)) << 4);
  }

  int aoff[8], boff[4];
#pragma unroll
  for (int mi = 0; mi < 8; ++mi) {
    int r = wm * 128 + mi * 16 + l15;
    aoff[mi] = r * 128 + ((lq ^ (r & 7)) << 4);
  }
#pragma unroll
  for (int ni = 0; ni < 4; ++ni) {
    int r = wn * 64 + ni * 16 + l15;
    boff[ni] = r * 128 + ((lq ^ (r & 7)) << 4);
  }

  f32x4 acc[8][4];
#pragma unroll
  for (int mi = 0; mi < 8; ++mi)
#pragma unroll
    for (int ni = 0; ni < 4; ++ni) acc[mi][ni] = (f32x4)(0.f);

  STG8(0, 0);
#pragma unroll 1
  for (int kt = 0; kt < NKT1; ++kt) {
    int d = kt & 1;
    if (kt + 1 < NKT1) { STG8(kt + 1, d ^ 1); VMCNT(8); }
    else { VMCNT(0); }
    __builtin_amdgcn_s_barrier();
    const char* Ab = ldsp + d * 32768;
    const char* Bb = ldsp + 65536 + d * 32768;
    KBODY(Ab, Bb);
    __builtin_amdgcn_s_barrier();
  }

  // GLU epilogue: up waves (wn>=2) dump u via LDS f32 [256][128] (swizzled),
  // gate waves compute silu(g)*u -> h (bf16)
  __syncthreads();
  float* xch = (float*)ldsp;
  int rbase = lq * 4;
  if (wn >= 2) {
    int uc0 = (wn - 2) * 64;
#pragma unroll
    for (int mi = 0; mi < 8; ++mi)
#pragma unroll
      for (int ni = 0; ni < 4; ++ni)
#pragma unroll
        for (int j = 0; j < 4; ++j) {
          int r = wm * 128 + mi * 16 + rbase + j;
          int c = uc0 + ni * 16 + l15;
          int cs = c ^ ((r & 3) << 2) ^ ((r & 1) << 4);
          xch[r * 128 + cs] = acc[mi][ni][j];
        }
  }
  __syncthreads();
  if (wn < 2) {
#pragma unroll
    for (int mi = 0; mi < 8; ++mi)
#pragma unroll
      for (int ni = 0; ni < 4; ++ni)
#pragma unroll
        for (int j = 0; j < 4; ++j) {
          int r = wm * 128 + mi * 16 + rbase + j;
          int c = wn * 64 + ni * 16 + l15;
          int cs = c ^ ((r & 3) << 2) ^ ((r & 1) << 4);
          float gg = acc[mi][ni][j];
          float u = xch[r * 128 + cs];
          float sv = gg / (1.f + expf(-gg));
          h[(size_t)(r0 + r) * HDIM + n0 + c] = f2bf(sv * u);
        }
  }
}

// =============== GEMM2: 256 slots x 256 D-cols, K=2816, yp bf16 ===============
__global__ __launch_bounds__(512, 1) void gemm2_k(const unsigned short* __restrict__ h,
                                                  const unsigned short* __restrict__ w2b,
                                                  const int* __restrict__ tile2exp,
                                                  const int* __restrict__ tilerow,
                                                  const int* __restrict__ ntiles,
                                                  unsigned short* __restrict__ yp) {
  __shared__ char ldsp[131072];
  int mt = blockIdx.x;
  if (mt >= ntiles[0]) return;
  int e = tile2exp[mt], r0 = tilerow[mt];
  int n0 = blockIdx.y * 256;
  int tid = threadIdx.x, lane = tid & 63;
  int wv = tid >> 6, wm = wv >> 2, wn = wv & 3;
  int l15 = lane & 15, lq = lane >> 4;

  int srow = tid >> 3, sq = tid & 7;
  const char* aSrc[4]; const char* bSrc[4];
#pragma unroll
  for (int u = 0; u < 4; ++u) {
    int r = srow + u * 64;
    aSrc[u] = (const char*)h + (size_t)(r0 + r) * (HDIM * 2) + ((sq ^ (r & 7)) << 4);
    bSrc[u] = (const char*)w2b + ((size_t)e * DDIM + n0 + r) * (HDIM * 2) + ((sq ^ (r & 7)) << 4);
  }

  int aoff[8], boff[4];
#pragma unroll
  for (int mi = 0; mi < 8; ++mi) {
    int r = wm * 128 + mi * 16 + l15;
    aoff[mi] = r * 128 + ((lq ^ (r & 7)) << 4);
  }
#pragma unroll
  for (int ni = 0; ni < 4; ++ni) {
    int r = wn * 64 + ni * 16 + l15;
    boff[ni] = r * 128 + ((lq ^ (r & 7)) << 4);
  }

  f32x4 acc[8][4];
#pragma unroll
  for (int mi = 0; mi < 8; ++mi)
#pragma unroll
    for (int ni = 0; ni < 4; ++ni) acc[mi][ni] = (f32x4)(0.f);

  STG8(0, 0);
#pragma unroll 1
  for (int kt = 0; kt < NKT2; ++kt) {
    int d = kt & 1;
    if (kt + 1 < NKT2) { STG8(kt + 1, d ^ 1); VMCNT(8); }
    else { VMCNT(0); }
    __builtin_amdgcn_s_barrier();
    const char* Ab = ldsp + d * 32768;
    const char* Bb = ldsp + 65536 + d * 32768;
    KBODY(Ab, Bb);
    __builtin_amdgcn_s_barrier();
  }

  int rbase = lq * 4;
#pragma unroll
  for (int mi = 0; mi < 8; ++mi)
#pragma unroll
    for (int ni = 0; ni < 4; ++ni)
#pragma unroll
      for (int j = 0; j < 4; ++j) {
        int r = r0 + wm * 128 + mi * 16 + rbase + j;
        int c = n0 + wn * 64 + ni * 16 + l15;
        yp[(size_t)r * DDIM + c] = f2bf(acc[mi][ni][j]);
      }
}

// ---------------- combine: y = w0*yp[s0] + w1*yp[s1] + bias ----------------
__global__ void combine_k(const unsigned short* __restrict__ yp, const float* __restrict__ wgt,
                          const int* __restrict__ slot, const float* __restrict__ bias,
                          float* __restrict__ out) {
  int idx = blockIdx.x * blockDim.x + threadIdx.x;
  int t = idx >> 8, q = (idx & 255) * 8;
  float w0 = wgt[2 * t], w1 = wgt[2 * t + 1];
  int s0 = slot[2 * t], s1 = slot[2 * t + 1];
  short8 a8 = *(const short8*)(yp + (size_t)s0 * DDIM + q);
  short8 b8 = *(const short8*)(yp + (size_t)s1 * DDIM + q);
  float* op = out + (size_t)t * DDIM + q;
#pragma unroll
  for (int k = 0; k < 8; ++k) {
    float av = bf2f((unsigned short)a8[k]);
    float bv = bf2f((unsigned short)b8[k]);
    op[k] = w0 * av + w1 * bv + bias[q + k];
  }
}

extern "C" void kernel_launch(void* const* d_in, const int* in_sizes, int n_in,
                              void* d_out, int out_size, void* d_ws, size_t ws_size,
                              hipStream_t stream) {
  const float* x    = (const float*)d_in[0];
  const float* w1   = (const float*)d_in[1];
  const float* w2   = (const float*)d_in[2];
  const float* rw   = (const float*)d_in[3];
  const float* bias = (const float*)d_in[4];
  float* out = (float*)d_out;

  char* ws = (char*)d_ws;
  size_t off = 0;
  auto alloc = [&](size_t bytes) -> void* {
    void* p = ws + off;
    off = (off + bytes + 255) & ~(size_t)255;
    return p;
  };
  unsigned short* w1b = (unsigned short*)alloc((size_t)NEXP * 2 * HDIM * DDIM * 2);
  unsigned short* w2b = (unsigned short*)alloc((size_t)NEXP * DDIM * HDIM * 2);
  unsigned short* xb  = (unsigned short*)alloc((size_t)M_TOK * DDIM * 2);
  unsigned short* h   = (unsigned short*)alloc((size_t)PMAX * HDIM * 2);
  unsigned short* yp  = (unsigned short*)alloc((size_t)PMAX * DDIM * 2);
  float* wgt          = (float*)alloc((size_t)M_TOK * 2 * 4);
  int* eid            = (int*)alloc((size_t)M_TOK * 2 * 4);
  int* slot           = (int*)alloc((size_t)M_TOK * 2 * 4);
  int* tok            = (int*)alloc((size_t)PMAX * 4);
  int* counts         = (int*)alloc(64 * 4);
  int* cursors        = (int*)alloc(64 * 4);
  int* offs           = (int*)alloc(64 * 4);
  int* ntiles         = (int*)alloc(64 * 4);
  int* tile2exp       = (int*)alloc(128 * 4);
  int* tilerow        = (int*)alloc(128 * 4);

  hipLaunchKernelGGL(cvt2_bf16_k, dim3(4096), dim3(256), 0, stream,
                     (const float4*)w1, (ushort4*)w1b, (int)((size_t)NEXP * 2 * HDIM * DDIM / 4),
                     (const float4*)w2, (ushort4*)w2b, (int)((size_t)NEXP * DDIM * HDIM / 4),
                     tok, counts, cursors);
  hipLaunchKernelGGL(router_k, dim3(M_TOK / 4), dim3(256), 0, stream,
                     (const float4*)x, (const float4*)rw, (ushort4*)xb, wgt, eid, counts);
  hipLaunchKernelGGL(offsets_k, dim3(1), dim3(64), 0, stream, counts, offs,
                     tile2exp, tilerow, ntiles);
  hipLaunchKernelGGL(scatter_k, dim3((M_TOK + 255) / 256), dim3(256), 0, stream, eid, offs, cursors, tok, slot);
  hipLaunchKernelGGL(gemm1_k, dim3(MAXTILES, NB1), dim3(512), 0, stream,
                     xb, w1b, tok, tile2exp, tilerow, ntiles, h);
  hipLaunchKernelGGL(gemm2_k, dim3(MAXTILES, NB2), dim3(512), 0, stream,
                     h, w2b, tile2exp, tilerow, ntiles, yp);
  hipLaunchKernelGGL(combine_k, dim3(M_TOK * (DDIM / 8) / 256), dim3(256), 0, stream, yp, wgt, slot, bias, out);
}